// Round 10
// baseline (2303.808 us; speedup 1.0000x reference)
//
#include <hip/hip_runtime.h>
#include <stdint.h>
#include <stddef.h>

#define B_ 128
#define T_ 256
#define I_ 256
#define H_ 1024
#define O_ 128

typedef __attribute__((ext_vector_type(8))) __bf16 bf16x8;
typedef __attribute__((ext_vector_type(4))) float f32x4;
typedef unsigned long long u64;

// Packed-swizzled layout for state/x (per buffer of K columns, 128 rows):
//   element (b,k): u64 idx = (b>>4)*(K/2)*16 + (k>>1)*16 + (b&15)
//   u64 = dword(k even) | dword(k odd)<<32 ; dword = hi_bits | lo_bits<<16
//
// h1[t] is aliased to layer0's state double-buffer; parity(t) buffer is only
// overwritten at layer0 round t+2, and the per-bt domain barrier (64 arrivals)
// at round t+1 orders layer1's readers first.  (R9 structure, session-best.)
//
// Round 10: counted-vmcnt asm load pipeline (PF=3). All step loads are
// inline-asm global_load_dwordx2 (sc1 for state/h1, plain for x) with manual
// s_waitcnt vmcnt(16/8/0) + sched_barrier(0). Loads complete in order, so
// "wait until <=N outstanding" always drains chunk c's loads even if
// compiler vmem interleaves (over-conservative, never unsafe).

// ---------------------------------------------------------------- setup

__global__ void split_kernel(const float* __restrict__ src, __bf16* __restrict__ hi,
                             __bf16* __restrict__ lo, int n) {
    int i = blockIdx.x * blockDim.x + threadIdx.x;
    int stride = gridDim.x * blockDim.x;
    for (; i < n; i += stride) {
        float v = src[i];
        __bf16 h = (__bf16)v;
        hi[i] = h;
        lo[i] = (__bf16)(v - (float)h);
    }
}

// X (B,T,I) fp32 -> packed-swizzled per t: xp[t][b>>4][k>>1][b&15]
__global__ void pack_x(const float* __restrict__ X, u64* __restrict__ xp) {
    int i = blockIdx.x * 256 + threadIdx.x;           // 0 .. 4194303
    int ln = i & 15;
    int k2 = (i >> 4) & 127;
    int bt16 = (i >> 11) & 7;
    int t = i >> 14;
    int b = bt16 * 16 + ln;
    long xo = (long)b * T_ * I_ + (long)t * I_ + k2 * 2;
    float v0 = X[xo], v1 = X[xo + 1];
    union { __bf16 b; unsigned short u; } h0, l0, h1, l1;
    h0.b = (__bf16)v0; l0.b = (__bf16)(v0 - (float)h0.b);
    h1.b = (__bf16)v1; l1.b = (__bf16)(v1 - (float)h1.b);
    u64 pk = (u64)((unsigned)h0.u | ((unsigned)l0.u << 16))
           | ((u64)((unsigned)h1.u | ((unsigned)l1.u << 16)) << 32);
    xp[(long)t * 16384 + bt16 * 2048 + k2 * 16 + ln] = pk;
}

__global__ void bias_sum_kernel(const float* __restrict__ a, const float* __restrict__ b,
                                float* __restrict__ o, int n) {
    int i = blockIdx.x * blockDim.x + threadIdx.x;
    if (i < n) o[i] = a[i] + b[i];
}

__global__ void transpose_fc(const float* __restrict__ w, float* __restrict__ wt) {
    int i = blockIdx.x * blockDim.x + threadIdx.x;
    if (i < O_ * H_) {
        int o = i / H_, k = i - o * H_;
        wt[k * O_ + o] = w[i];
    }
}

// ---------------------------------------------------------------- loaders

__device__ __forceinline__ void unpack4(const u64* d, bf16x8* hi, bf16x8* lo) {
    union { unsigned u[4]; bf16x8 v; } Hh, Ll;
    #pragma unroll
    for (int i = 0; i < 4; ++i) {
        unsigned lo32 = (unsigned)d[i], hi32 = (unsigned)(d[i] >> 32);
        Hh.u[i] = (lo32 & 0xFFFFu) | (hi32 << 16);
        Ll.u[i] = (lo32 >> 16) | (hi32 & 0xFFFF0000u);
    }
    *hi = Hh.v; *lo = Ll.v;
}

// 4 x 8B asm loads at byte offsets 0/128/256/384. sc1 = agent(LLC)-coherent.
// No waitcnt here: caller performs counted s_waitcnt before consuming.
__device__ __forceinline__ void load4_sc1(const u64* p, u64* d) {
    asm volatile("global_load_dwordx2 %0, %1, off sc1"            : "=&v"(d[0]) : "v"(p));
    asm volatile("global_load_dwordx2 %0, %1, off offset:128 sc1" : "=&v"(d[1]) : "v"(p));
    asm volatile("global_load_dwordx2 %0, %1, off offset:256 sc1" : "=&v"(d[2]) : "v"(p));
    asm volatile("global_load_dwordx2 %0, %1, off offset:384 sc1" : "=&v"(d[3]) : "v"(p));
}

// plain cached variant (x: written before kernel launch, LLC-visible)
__device__ __forceinline__ void load4_cached(const u64* p, u64* d) {
    asm volatile("global_load_dwordx2 %0, %1, off"            : "=&v"(d[0]) : "v"(p));
    asm volatile("global_load_dwordx2 %0, %1, off offset:128" : "=&v"(d[1]) : "v"(p));
    asm volatile("global_load_dwordx2 %0, %1, off offset:256" : "=&v"(d[2]) : "v"(p));
    asm volatile("global_load_dwordx2 %0, %1, off offset:384" : "=&v"(d[3]) : "v"(p));
}

// ---------------------------------------------------------------- step
// One layer step for one 32x32 tile. W register-resident (wh/wl), K-split 8.
// CPW chunks of 32 k per wave; chunks [0,SEG0CH) = seg0 (A0), rest = state.
// PF=3 counted-vmcnt pipeline: 24 loads in flight, wait vmcnt(16) steady.
template <int CPW, int SEG0CH, bool CACHED0>
__device__ __forceinline__ void step_full(
    const u64* __restrict__ A0,            // packed seg0 (xp_t or h1 alias)
    const u64* __restrict__ Sp,            // packed state (K=1024)
    const bf16x8 (&wh)[CPW][2], const bf16x8 (&wl)[CPW][2],
    const float* __restrict__ bs,
    u64* __restrict__ So,
    int bt, int jt, int w, float* red)
{
    const int lane = threadIdx.x & 63;
    const int ln = lane & 15;
    const int q  = lane >> 4;

    // preload epilogue bias before the counted region (oldest vmem, drains
    // under the first counted wait; keeps compiler vmem out of the pipeline)
    const int tid = threadIdx.x;
    const int erow = tid & 31;
    const int ejp  = tid >> 5;
    const int ec0  = ejp * 2;
    const int ej0  = jt * 32 + ec0;
    float bsv0 = bs[ej0];
    float bsv1 = bs[ej0 + 1];

    f32x4 acc[2][2][2];
    #pragma unroll
    for (int s = 0; s < 2; ++s)
        #pragma unroll
        for (int n = 0; n < 2; ++n)
            #pragma unroll
            for (int r = 0; r < 2; ++r)
                acc[s][n][r] = (f32x4){0.f, 0.f, 0.f, 0.f};

    constexpr int PF = 3;                  // pipeline depth (chunks)
    u64 d[PF][2][4];

    auto issue = [&](int c, u64 (&dst)[2][4]) {
        const int gC = w * CPW + c;
        if (gC < SEG0CH) {
            const u64* base = A0 + (long)(gC * 16 + q * 4) * 16 + ln;
            #pragma unroll
            for (int s = 0; s < 2; ++s) {
                const u64* p = base + (long)(bt * 2 + s) * (SEG0CH * 256);
                if (CACHED0) load4_cached(p, dst[s]);
                else         load4_sc1(p, dst[s]);
            }
        } else {
            const u64* base = Sp + (long)((gC - SEG0CH) * 16 + q * 4) * 16 + ln;
            #pragma unroll
            for (int s = 0; s < 2; ++s) {
                const u64* p = base + (long)(bt * 2 + s) * 8192;
                load4_sc1(p, dst[s]);
            }
        }
    };

    issue(0, d[0]);
    issue(1, d[1]);
    issue(2, d[2]);                        // CPW >= 3 always (5 or 8)

    #pragma unroll
    for (int c = 0; c < CPW; ++c) {
        // counted wait: drain chunk c's 8 loads, keep the newer (PF-1)*8
        const int rem = CPW - 1 - c;
        if (rem >= 2)      { asm volatile("s_waitcnt vmcnt(16)" ::: "memory"); }
        else if (rem == 1) { asm volatile("s_waitcnt vmcnt(8)"  ::: "memory"); }
        else               { asm volatile("s_waitcnt vmcnt(0)"  ::: "memory"); }
        __builtin_amdgcn_sched_barrier(0);   // rule #18: pin unpack after wait

        bf16x8 ah[2], al[2];
        #pragma unroll
        for (int s = 0; s < 2; ++s)
            unpack4(d[c % PF][s], &ah[s], &al[s]);
        if (c + PF < CPW) issue(c + PF, d[c % PF]);
        #pragma unroll
        for (int s = 0; s < 2; ++s)
            #pragma unroll
            for (int n = 0; n < 2; ++n) {
                acc[s][n][0] = __builtin_amdgcn_mfma_f32_16x16x32_bf16(ah[s], wh[c][n], acc[s][n][0], 0, 0, 0);
                acc[s][n][1] = __builtin_amdgcn_mfma_f32_16x16x32_bf16(al[s], wh[c][n], acc[s][n][1], 0, 0, 0);
                acc[s][n][1] = __builtin_amdgcn_mfma_f32_16x16x32_bf16(ah[s], wl[c][n], acc[s][n][1], 0, 0, 0);
            }
    }

    // LDS reduce over 8 K-split waves (pad 33)
    {
        float* my = red + w * 1056;
        #pragma unroll
        for (int s = 0; s < 2; ++s)
            #pragma unroll
            for (int n = 0; n < 2; ++n) {
                f32x4 sum = acc[s][n][0] + acc[s][n][1];
                #pragma unroll
                for (int r = 0; r < 4; ++r)       // C/D: col=ln, row=q*4+r
                    my[(s * 16 + q * 4 + r) * 33 + n * 16 + ln] = sum[r];
            }
    }
    __syncthreads();

    // epilogue: 1024 outputs = 512 u64 (pairs), one per thread
    {
        float v0 = 0.f, v1 = 0.f;
        #pragma unroll
        for (int w8 = 0; w8 < 8; ++w8) {
            v0 += red[w8 * 1056 + erow * 33 + ec0];
            v1 += red[w8 * 1056 + erow * 33 + ec0 + 1];
        }
        float h0 = tanhf(v0 + bsv0);
        float h1v = tanhf(v1 + bsv1);
        union { __bf16 b; unsigned short u; } x0h, x0l, x1h, x1l;
        x0h.b = (__bf16)h0;  x0l.b = (__bf16)(h0 - (float)x0h.b);
        x1h.b = (__bf16)h1v; x1l.b = (__bf16)(h1v - (float)x1h.b);
        u64 pk = (u64)((unsigned)x0h.u | ((unsigned)x0l.u << 16))
               | ((u64)((unsigned)x1h.u | ((unsigned)x1l.u << 16)) << 32);
        long idx = (long)(bt * 2 + (erow >> 4)) * 8192 + (long)(jt * 16 + ejp) * 16 + (erow & 15);
        __hip_atomic_store(&So[idx], pk, __ATOMIC_RELAXED, __HIP_MEMORY_SCOPE_AGENT);
    }
}

// ---------------------------------------------------------------- barrier
// Per-bt domain barrier: 64 blocks (32 layer0 + 32 layer1 sharing the same
// 32 batch rows). Single level: one arrive counter + one release flag per
// domain, on separate LLC lines. Fence-free (relaxed agent atomics meet at
// LLC); vmcnt drain before arrive guarantees stores are LLC-visible.
__device__ __forceinline__ void domain_barrier(unsigned* bar, int dom, unsigned step) {
    asm volatile("s_waitcnt vmcnt(0)" ::: "memory");
    __syncthreads();
    if (threadIdx.x == 0) {
        unsigned tgt = step + 1u;
        unsigned old = __hip_atomic_fetch_add(&bar[dom * 64], 1u, __ATOMIC_RELAXED,
                                              __HIP_MEMORY_SCOPE_AGENT);
        if (old == step * 64u + 63u)
            __hip_atomic_store(&bar[dom * 64 + 32], tgt, __ATOMIC_RELAXED,
                               __HIP_MEMORY_SCOPE_AGENT);
        while (__hip_atomic_load(&bar[dom * 64 + 32], __ATOMIC_RELAXED,
                                 __HIP_MEMORY_SCOPE_AGENT) < tgt)
            __builtin_amdgcn_s_sleep(2);
    }
    __syncthreads();
    asm volatile("" ::: "memory");
}

// ---------------------------------------------------------------- persistent
struct PArgs {
    const u64* xp;                        // packed X [t][bt16][k2][ln]
    const __bf16 *Wi0h, *Wi0l, *Wr0h, *Wr0l;
    const __bf16 *Wi1h, *Wi1l, *Wr1h, *Wr1l;
    const float *bs0, *bs1;
    u64 *s0a, *s0b, *s1a, *s1b;           // s0* doubles as h1 (aliased)
    unsigned* bar;
};

// 256 blocks x 512 threads (8 waves), 1 block/CU. 128 layer0 + 128 layer1
// blocks; per layer tiles: 4 bt (m=32) x 32 jt (n=32), K-split 8 over waves.
// Weights live in registers for the whole run (preloaded once).
__global__ __launch_bounds__(512, 2) void persistent_rnn(PArgs a) {
    __shared__ float red[8 * 1056];
    const int w = threadIdx.x >> 6;
    const int lane = threadIdx.x & 63;
    const int ln = lane & 15;
    const int q  = lane >> 4;
    const int layer = blockIdx.x >> 7;
    const int r7 = blockIdx.x & 127;
    const int jt = r7 & 31;
    const int bt = r7 >> 5;

    if (layer == 0) {
        // ---- preload W slice: chunks w*5 .. w*5+4 of Ktot=1280 (8 x-chunks, 32 rec)
        bf16x8 wh[5][2], wl[5][2];
        #pragma unroll
        for (int c = 0; c < 5; ++c) {
            int gC = w * 5 + c;
            #pragma unroll
            for (int n = 0; n < 2; ++n) {
                int jr = jt * 32 + n * 16 + ln;
                if (gC < 8) {
                    wh[c][n] = *(const bf16x8*)(a.Wi0h + (long)jr * 256 + gC * 32 + q * 8);
                    wl[c][n] = *(const bf16x8*)(a.Wi0l + (long)jr * 256 + gC * 32 + q * 8);
                } else {
                    wh[c][n] = *(const bf16x8*)(a.Wr0h + (long)jr * 1024 + (gC - 8) * 32 + q * 8);
                    wl[c][n] = *(const bf16x8*)(a.Wr0l + (long)jr * 1024 + (gC - 8) * 32 + q * 8);
                }
            }
        }
        for (int t = 0; t < T_; ++t) {
            const u64* sin = (t & 1) ? a.s0b : a.s0a;
            u64* sout      = (t & 1) ? a.s0a : a.s0b;
            step_full<5, 8, true>(a.xp + (long)t * 16384, sin, wh, wl, a.bs0,
                                  sout, bt, jt, w, red);
            domain_barrier(a.bar, bt, (unsigned)t);
        }
    } else {
        // ---- preload W slice: chunks w*8 .. w*8+7 of Ktot=2048 (32 h1, 32 rec)
        bf16x8 wh[8][2], wl[8][2];
        #pragma unroll
        for (int c = 0; c < 8; ++c) {
            int gC = w * 8 + c;
            #pragma unroll
            for (int n = 0; n < 2; ++n) {
                int jr = jt * 32 + n * 16 + ln;
                if (gC < 32) {
                    wh[c][n] = *(const bf16x8*)(a.Wi1h + (long)jr * 1024 + gC * 32 + q * 8);
                    wl[c][n] = *(const bf16x8*)(a.Wi1l + (long)jr * 1024 + gC * 32 + q * 8);
                } else {
                    wh[c][n] = *(const bf16x8*)(a.Wr1h + (long)jr * 1024 + (gC - 32) * 32 + q * 8);
                    wl[c][n] = *(const bf16x8*)(a.Wr1l + (long)jr * 1024 + (gC - 32) * 32 + q * 8);
                }
            }
        }
        domain_barrier(a.bar, bt, 0u);
        for (int t = 1; t <= T_; ++t) {
            int t1 = t - 1;
            // h1[t1] aliases layer0's sout of round t1: parity buffer
            const u64* h1in = (t1 & 1) ? a.s0a : a.s0b;
            const u64* sin  = (t1 & 1) ? a.s1b : a.s1a;
            u64* sout       = (t1 & 1) ? a.s1a : a.s1b;
            step_full<8, 32, false>(h1in, sin, wh, wl, a.bs1,
                                    sout, bt, jt, w, red);
            if (t < T_) domain_barrier(a.bar, bt, (unsigned)t);
        }
    }
}

// ---------------------------------------------------------------- final FC
__global__ __launch_bounds__(128) void fc_kernel(const u64* __restrict__ sp,
                                                 const float* __restrict__ wt,
                                                 const float* __restrict__ bfc,
                                                 float* __restrict__ out) {
    int b = blockIdx.x;
    int o = threadIdx.x;
    int bt = b >> 4, r = b & 15;
    float acc = 0.f;
    #pragma unroll 4
    for (int k2 = 0; k2 < H_ / 2; ++k2) {
        u64 pk = __hip_atomic_load((u64*)sp + (long)bt * 8192 + (long)k2 * 16 + r,
                                   __ATOMIC_RELAXED, __HIP_MEMORY_SCOPE_AGENT);
        union { unsigned short u; __bf16 bf; } hh, hl;
        unsigned lo32 = (unsigned)pk, hi32 = (unsigned)(pk >> 32);
        hh.u = (unsigned short)(lo32 & 0xFFFF); hl.u = (unsigned short)(lo32 >> 16);
        float x0 = (float)hh.bf + (float)hl.bf;
        hh.u = (unsigned short)(hi32 & 0xFFFF); hl.u = (unsigned short)(hi32 >> 16);
        float x1 = (float)hh.bf + (float)hl.bf;
        acc += x0 * wt[(2 * k2) * O_ + o] + x1 * wt[(2 * k2 + 1) * O_ + o];
    }
    out[b * O_ + o] = acc + bfc[o];
}

// ---------------------------------------------------------------- launch

extern "C" void kernel_launch(void* const* d_in, const int* in_sizes, int n_in,
                              void* d_out, int out_size, void* d_ws, size_t ws_size,
                              hipStream_t stream) {
    const float* X     = (const float*)d_in[0];
    const float* Wih0  = (const float*)d_in[1];
    const float* Whh0  = (const float*)d_in[2];
    const float* bih0  = (const float*)d_in[3];
    const float* bhh0  = (const float*)d_in[4];
    const float* Wih1  = (const float*)d_in[5];
    const float* Whh1  = (const float*)d_in[6];
    const float* bih1  = (const float*)d_in[7];
    const float* bhh1  = (const float*)d_in[8];
    const float* Wfc   = (const float*)d_in[9];
    const float* bfc   = (const float*)d_in[10];
    float* out = (float*)d_out;

    char* p = (char*)d_ws;
    auto alloc = [&](size_t bytes) -> void* {
        void* r = (void*)p;
        p += (bytes + 255) & ~(size_t)255;
        return r;
    };
    const size_t nW0 = (size_t)H_ * I_;
    const size_t nW  = (size_t)H_ * H_;
    u64* xp      = (u64*)alloc((size_t)T_ * 16384 * 8);     // 33.5 MB
    __bf16* W0h  = (__bf16*)alloc(nW0 * 2);
    __bf16* W0l  = (__bf16*)alloc(nW0 * 2);
    __bf16* Wh0h = (__bf16*)alloc(nW * 2);
    __bf16* Wh0l = (__bf16*)alloc(nW * 2);
    __bf16* Wi1h = (__bf16*)alloc(nW * 2);
    __bf16* Wi1l = (__bf16*)alloc(nW * 2);
    __bf16* Wh1h = (__bf16*)alloc(nW * 2);
    __bf16* Wh1l = (__bf16*)alloc(nW * 2);
    u64* s0a  = (u64*)alloc(65536 * 8);
    u64* s0b  = (u64*)alloc(65536 * 8);
    u64* s1a  = (u64*)alloc(65536 * 8);
    u64* s1b  = (u64*)alloc(65536 * 8);
    float* wfct = (float*)alloc((size_t)H_ * O_ * 4);
    float* bs0  = (float*)alloc((size_t)H_ * 4);
    float* bs1  = (float*)alloc((size_t)H_ * 4);
    unsigned* bar = (unsigned*)alloc(4096);
    (void)ws_size; (void)n_in; (void)in_sizes; (void)out_size;

    pack_x<<<16384, 256, 0, stream>>>(X, xp);
    split_kernel<<<512, 256, 0, stream>>>(Wih0, W0h, W0l, (int)nW0);
    split_kernel<<<1024, 256, 0, stream>>>(Whh0, Wh0h, Wh0l, (int)nW);
    split_kernel<<<1024, 256, 0, stream>>>(Wih1, Wi1h, Wi1l, (int)nW);
    split_kernel<<<1024, 256, 0, stream>>>(Whh1, Wh1h, Wh1l, (int)nW);
    bias_sum_kernel<<<4, 256, 0, stream>>>(bih0, bhh0, bs0, H_);
    bias_sum_kernel<<<4, 256, 0, stream>>>(bih1, bhh1, bs1, H_);
    transpose_fc<<<(O_ * H_ + 255) / 256, 256, 0, stream>>>(Wfc, wfct);

    hipMemsetAsync(s0a, 0, 65536 * 8, stream);
    hipMemsetAsync(s1a, 0, 65536 * 8, stream);
    hipMemsetAsync(bar, 0, 4096, stream);

    PArgs args;
    args.xp = xp;
    args.Wi0h = W0h; args.Wi0l = W0l; args.Wr0h = Wh0h; args.Wr0l = Wh0l;
    args.Wi1h = Wi1h; args.Wi1l = Wi1l; args.Wr1h = Wh1h; args.Wr1l = Wh1l;
    args.bs0 = bs0; args.bs1 = bs1;
    args.s0a = s0a; args.s0b = s0b; args.s1a = s1a; args.s1b = s1b;
    args.bar = bar;
    void* kp[] = { &args };
    hipLaunchCooperativeKernel((void*)persistent_rnn, dim3(256), dim3(512), kp, 0, stream);

    // final layer1 state: last t1=255 (odd) wrote s1a
    fc_kernel<<<B_, O_, 0, stream>>>(s1a, wfct, bfc, out);
}

// Round 11
// 1934.739 us; speedup vs baseline: 1.1908x; 1.1908x over previous
//
#include <hip/hip_runtime.h>
#include <stdint.h>
#include <stddef.h>

#define B_ 128
#define T_ 256
#define I_ 256
#define H_ 1024
#define O_ 128

typedef __attribute__((ext_vector_type(8))) __bf16 bf16x8;
typedef __attribute__((ext_vector_type(4))) float f32x4;
typedef unsigned long long u64;

// Packed-swizzled layout for state/x (per buffer of K columns, 128 rows):
//   element (b,k): u64 idx = (b>>4)*(K/2)*16 + (k>>1)*16 + (b&15)
//   u64 = dword(k even) | dword(k odd)<<32 ; dword = hi_bits | lo_bits<<16
//
// h1[t] is aliased to layer0's state double-buffer (identical content &
// layout); parity(t) buffer is only overwritten at layer0 round t+2, and
// the per-bt domain barrier (64 arrivals: 32 L0 + 32 L1 blocks) at round
// t+1 orders layer1's round-(t+1) readers first.
//
// Session-best structure (R9: 1856us steady): R1 joint domain barrier +
// packed-u64 interleaved layout + PF=2 compiler-scheduled loads + merged
// low-order accumulator. Ten rounds of levers (PF depth, store density,
// wave-granular waits, producer flags, L2-caching via acquire fences,
// counted-vmcnt asm pipeline) all null or regress: the kernel is bound by
// the agent-scope LLC read path (~50MB/round at ~7TB/s, x32 jt-block
// amplification irreducible within the register/LDS/precision budget).

// ---------------------------------------------------------------- setup

__global__ void split_kernel(const float* __restrict__ src, __bf16* __restrict__ hi,
                             __bf16* __restrict__ lo, int n) {
    int i = blockIdx.x * blockDim.x + threadIdx.x;
    int stride = gridDim.x * blockDim.x;
    for (; i < n; i += stride) {
        float v = src[i];
        __bf16 h = (__bf16)v;
        hi[i] = h;
        lo[i] = (__bf16)(v - (float)h);
    }
}

// X (B,T,I) fp32 -> packed-swizzled per t: xp[t][b>>4][k>>1][b&15]
__global__ void pack_x(const float* __restrict__ X, u64* __restrict__ xp) {
    int i = blockIdx.x * 256 + threadIdx.x;           // 0 .. 4194303
    int ln = i & 15;
    int k2 = (i >> 4) & 127;
    int bt16 = (i >> 11) & 7;
    int t = i >> 14;
    int b = bt16 * 16 + ln;
    long xo = (long)b * T_ * I_ + (long)t * I_ + k2 * 2;
    float v0 = X[xo], v1 = X[xo + 1];
    union { __bf16 b; unsigned short u; } h0, l0, h1, l1;
    h0.b = (__bf16)v0; l0.b = (__bf16)(v0 - (float)h0.b);
    h1.b = (__bf16)v1; l1.b = (__bf16)(v1 - (float)h1.b);
    u64 pk = (u64)((unsigned)h0.u | ((unsigned)l0.u << 16))
           | ((u64)((unsigned)h1.u | ((unsigned)l1.u << 16)) << 32);
    xp[(long)t * 16384 + bt16 * 2048 + k2 * 16 + ln] = pk;
}

__global__ void bias_sum_kernel(const float* __restrict__ a, const float* __restrict__ b,
                                float* __restrict__ o, int n) {
    int i = blockIdx.x * blockDim.x + threadIdx.x;
    if (i < n) o[i] = a[i] + b[i];
}

__global__ void transpose_fc(const float* __restrict__ w, float* __restrict__ wt) {
    int i = blockIdx.x * blockDim.x + threadIdx.x;
    if (i < O_ * H_) {
        int o = i / H_, k = i - o * H_;
        wt[k * O_ + o] = w[i];
    }
}

// ---------------------------------------------------------------- loaders

__device__ __forceinline__ void unpack4(const u64* d, bf16x8* hi, bf16x8* lo) {
    union { unsigned u[4]; bf16x8 v; } Hh, Ll;
    #pragma unroll
    for (int i = 0; i < 4; ++i) {
        unsigned lo32 = (unsigned)d[i], hi32 = (unsigned)(d[i] >> 32);
        Hh.u[i] = (lo32 & 0xFFFFu) | (hi32 << 16);
        Ll.u[i] = (lo32 >> 16) | (hi32 & 0xFFFF0000u);
    }
    *hi = Hh.v; *lo = Ll.v;
}

// sc1 LLC-coherent loads (state/h1 written mid-kernel by other blocks)
__device__ __forceinline__ void load_swz(const u64* p, bf16x8* hi, bf16x8* lo) {
    u64 d[4];
    #pragma unroll
    for (int i = 0; i < 4; ++i)
        d[i] = __hip_atomic_load((u64*)p + i * 16, __ATOMIC_RELAXED,
                                 __HIP_MEMORY_SCOPE_AGENT);
    unpack4(d, hi, lo);
}

// plain cached loads (x: written before kernel launch, LLC-visible)
__device__ __forceinline__ void load_swz_cached(const u64* p, bf16x8* hi, bf16x8* lo) {
    u64 d[4];
    #pragma unroll
    for (int i = 0; i < 4; ++i)
        d[i] = p[i * 16];
    unpack4(d, hi, lo);
}

// ---------------------------------------------------------------- step
// One layer step for one 32x32 tile. W register-resident (wh/wl), K-split 8.
// CPW chunks of 32 k per wave; chunks [0,SEG0CH) = seg0 (A0), rest = state.
template <int CPW, int SEG0CH, bool CACHED0>
__device__ __forceinline__ void step_full(
    const u64* __restrict__ A0,            // packed seg0 (xp_t or h1 alias)
    const u64* __restrict__ Sp,            // packed state (K=1024)
    const bf16x8 (&wh)[CPW][2], const bf16x8 (&wl)[CPW][2],
    const float* __restrict__ bs,
    u64* __restrict__ So,
    int bt, int jt, int w, float* red)
{
    const int lane = threadIdx.x & 63;
    const int ln = lane & 15;
    const int q  = lane >> 4;

    f32x4 acc[2][2][2];
    #pragma unroll
    for (int s = 0; s < 2; ++s)
        #pragma unroll
        for (int n = 0; n < 2; ++n)
            #pragma unroll
            for (int r = 0; r < 2; ++r)
                acc[s][n][r] = (f32x4){0.f, 0.f, 0.f, 0.f};

    constexpr int PF = 2;                  // pipeline depth (chunks)
    u64 d[PF][2][4];

    auto issue = [&](int c, u64 (&dst)[2][4]) {
        const int gC = w * CPW + c;
        if (gC < SEG0CH) {
            const u64* base = A0 + (long)(gC * 16 + q * 4) * 16 + ln;
            #pragma unroll
            for (int s = 0; s < 2; ++s) {
                const u64* p = base + (long)(bt * 2 + s) * (SEG0CH * 256);
                #pragma unroll
                for (int i = 0; i < 4; ++i) {
                    if (CACHED0) dst[s][i] = p[i * 16];
                    else dst[s][i] = __hip_atomic_load((u64*)p + i * 16,
                                         __ATOMIC_RELAXED, __HIP_MEMORY_SCOPE_AGENT);
                }
            }
        } else {
            const u64* base = Sp + (long)((gC - SEG0CH) * 16 + q * 4) * 16 + ln;
            #pragma unroll
            for (int s = 0; s < 2; ++s) {
                const u64* p = base + (long)(bt * 2 + s) * 8192;
                #pragma unroll
                for (int i = 0; i < 4; ++i)
                    dst[s][i] = __hip_atomic_load((u64*)p + i * 16,
                                    __ATOMIC_RELAXED, __HIP_MEMORY_SCOPE_AGENT);
            }
        }
    };

    issue(0, d[0]);
    issue(1, d[1]);                        // CPW >= 2 always (5 or 8)

    #pragma unroll
    for (int c = 0; c < CPW; ++c) {
        bf16x8 ah[2], al[2];
        #pragma unroll
        for (int s = 0; s < 2; ++s)
            unpack4(d[c & 1][s], &ah[s], &al[s]);
        if (c + PF < CPW) issue(c + PF, d[c & 1]);
        #pragma unroll
        for (int s = 0; s < 2; ++s)
            #pragma unroll
            for (int n = 0; n < 2; ++n) {
                acc[s][n][0] = __builtin_amdgcn_mfma_f32_16x16x32_bf16(ah[s], wh[c][n], acc[s][n][0], 0, 0, 0);
                acc[s][n][1] = __builtin_amdgcn_mfma_f32_16x16x32_bf16(al[s], wh[c][n], acc[s][n][1], 0, 0, 0);
                acc[s][n][1] = __builtin_amdgcn_mfma_f32_16x16x32_bf16(ah[s], wl[c][n], acc[s][n][1], 0, 0, 0);
            }
    }

    // LDS reduce over 8 K-split waves (pad 33)
    {
        float* my = red + w * 1056;
        #pragma unroll
        for (int s = 0; s < 2; ++s)
            #pragma unroll
            for (int n = 0; n < 2; ++n) {
                f32x4 sum = acc[s][n][0] + acc[s][n][1];
                #pragma unroll
                for (int r = 0; r < 4; ++r)       // C/D: col=ln, row=q*4+r
                    my[(s * 16 + q * 4 + r) * 33 + n * 16 + ln] = sum[r];
            }
    }
    __syncthreads();

    // epilogue: 1024 outputs = 512 u64 (pairs), one per thread
    {
        int tid = threadIdx.x;
        int row = tid & 31;
        int jp  = tid >> 5;                 // 0..15
        int c0 = jp * 2;
        float v0 = 0.f, v1 = 0.f;
        #pragma unroll
        for (int w8 = 0; w8 < 8; ++w8) {
            v0 += red[w8 * 1056 + row * 33 + c0];
            v1 += red[w8 * 1056 + row * 33 + c0 + 1];
        }
        int j0 = jt * 32 + c0;
        float h0 = tanhf(v0 + bs[j0]);
        float h1v = tanhf(v1 + bs[j0 + 1]);
        union { __bf16 b; unsigned short u; } x0h, x0l, x1h, x1l;
        x0h.b = (__bf16)h0;  x0l.b = (__bf16)(h0 - (float)x0h.b);
        x1h.b = (__bf16)h1v; x1l.b = (__bf16)(h1v - (float)x1h.b);
        u64 pk = (u64)((unsigned)x0h.u | ((unsigned)x0l.u << 16))
               | ((u64)((unsigned)x1h.u | ((unsigned)x1l.u << 16)) << 32);
        long idx = (long)(bt * 2 + (row >> 4)) * 8192 + (long)(jt * 16 + jp) * 16 + (row & 15);
        __hip_atomic_store(&So[idx], pk, __ATOMIC_RELAXED, __HIP_MEMORY_SCOPE_AGENT);
    }
}

// ---------------------------------------------------------------- barrier
// Per-bt domain barrier: 64 blocks (32 layer0 + 32 layer1 sharing the same
// 32 batch rows). Single level: one arrive counter + one release flag per
// domain, on separate LLC lines. Fence-free (relaxed agent atomics meet at
// LLC); vmcnt drain before arrive guarantees stores are LLC-visible.
__device__ __forceinline__ void domain_barrier(unsigned* bar, int dom, unsigned step) {
    asm volatile("s_waitcnt vmcnt(0)" ::: "memory");
    __syncthreads();
    if (threadIdx.x == 0) {
        unsigned tgt = step + 1u;
        unsigned old = __hip_atomic_fetch_add(&bar[dom * 64], 1u, __ATOMIC_RELAXED,
                                              __HIP_MEMORY_SCOPE_AGENT);
        if (old == step * 64u + 63u)
            __hip_atomic_store(&bar[dom * 64 + 32], tgt, __ATOMIC_RELAXED,
                               __HIP_MEMORY_SCOPE_AGENT);
        while (__hip_atomic_load(&bar[dom * 64 + 32], __ATOMIC_RELAXED,
                                 __HIP_MEMORY_SCOPE_AGENT) < tgt)
            __builtin_amdgcn_s_sleep(2);
    }
    __syncthreads();
    asm volatile("" ::: "memory");
}

// ---------------------------------------------------------------- persistent
struct PArgs {
    const u64* xp;                        // packed X [t][bt16][k2][ln]
    const __bf16 *Wi0h, *Wi0l, *Wr0h, *Wr0l;
    const __bf16 *Wi1h, *Wi1l, *Wr1h, *Wr1l;
    const float *bs0, *bs1;
    u64 *s0a, *s0b, *s1a, *s1b;           // s0* doubles as h1 (aliased)
    unsigned* bar;
};

// 256 blocks x 512 threads (8 waves), 1 block/CU. 128 layer0 + 128 layer1
// blocks; per layer tiles: 4 bt (m=32) x 32 jt (n=32), K-split 8 over waves.
// Weights live in registers for the whole run (preloaded once).
__global__ __launch_bounds__(512, 2) void persistent_rnn(PArgs a) {
    __shared__ float red[8 * 1056];
    const int w = threadIdx.x >> 6;
    const int lane = threadIdx.x & 63;
    const int ln = lane & 15;
    const int q  = lane >> 4;
    const int layer = blockIdx.x >> 7;
    const int r7 = blockIdx.x & 127;
    const int jt = r7 & 31;
    const int bt = r7 >> 5;

    if (layer == 0) {
        // ---- preload W slice: chunks w*5 .. w*5+4 of Ktot=1280 (8 x-chunks, 32 rec)
        bf16x8 wh[5][2], wl[5][2];
        #pragma unroll
        for (int c = 0; c < 5; ++c) {
            int gC = w * 5 + c;
            #pragma unroll
            for (int n = 0; n < 2; ++n) {
                int jr = jt * 32 + n * 16 + ln;
                if (gC < 8) {
                    wh[c][n] = *(const bf16x8*)(a.Wi0h + (long)jr * 256 + gC * 32 + q * 8);
                    wl[c][n] = *(const bf16x8*)(a.Wi0l + (long)jr * 256 + gC * 32 + q * 8);
                } else {
                    wh[c][n] = *(const bf16x8*)(a.Wr0h + (long)jr * 1024 + (gC - 8) * 32 + q * 8);
                    wl[c][n] = *(const bf16x8*)(a.Wr0l + (long)jr * 1024 + (gC - 8) * 32 + q * 8);
                }
            }
        }
        for (int t = 0; t < T_; ++t) {
            const u64* sin = (t & 1) ? a.s0b : a.s0a;
            u64* sout      = (t & 1) ? a.s0a : a.s0b;
            step_full<5, 8, true>(a.xp + (long)t * 16384, sin, wh, wl, a.bs0,
                                  sout, bt, jt, w, red);
            domain_barrier(a.bar, bt, (unsigned)t);
        }
    } else {
        // ---- preload W slice: chunks w*8 .. w*8+7 of Ktot=2048 (32 h1, 32 rec)
        bf16x8 wh[8][2], wl[8][2];
        #pragma unroll
        for (int c = 0; c < 8; ++c) {
            int gC = w * 8 + c;
            #pragma unroll
            for (int n = 0; n < 2; ++n) {
                int jr = jt * 32 + n * 16 + ln;
                if (gC < 32) {
                    wh[c][n] = *(const bf16x8*)(a.Wi1h + (long)jr * 1024 + gC * 32 + q * 8);
                    wl[c][n] = *(const bf16x8*)(a.Wi1l + (long)jr * 1024 + gC * 32 + q * 8);
                } else {
                    wh[c][n] = *(const bf16x8*)(a.Wr1h + (long)jr * 1024 + (gC - 32) * 32 + q * 8);
                    wl[c][n] = *(const bf16x8*)(a.Wr1l + (long)jr * 1024 + (gC - 32) * 32 + q * 8);
                }
            }
        }
        domain_barrier(a.bar, bt, 0u);
        for (int t = 1; t <= T_; ++t) {
            int t1 = t - 1;
            // h1[t1] aliases layer0's sout of round t1: parity buffer
            const u64* h1in = (t1 & 1) ? a.s0a : a.s0b;
            const u64* sin  = (t1 & 1) ? a.s1b : a.s1a;
            u64* sout       = (t1 & 1) ? a.s1a : a.s1b;
            step_full<8, 32, false>(h1in, sin, wh, wl, a.bs1,
                                    sout, bt, jt, w, red);
            if (t < T_) domain_barrier(a.bar, bt, (unsigned)t);
        }
    }
}

// ---------------------------------------------------------------- final FC
__global__ __launch_bounds__(128) void fc_kernel(const u64* __restrict__ sp,
                                                 const float* __restrict__ wt,
                                                 const float* __restrict__ bfc,
                                                 float* __restrict__ out) {
    int b = blockIdx.x;
    int o = threadIdx.x;
    int bt = b >> 4, r = b & 15;
    float acc = 0.f;
    #pragma unroll 4
    for (int k2 = 0; k2 < H_ / 2; ++k2) {
        u64 pk = __hip_atomic_load((u64*)sp + (long)bt * 8192 + (long)k2 * 16 + r,
                                   __ATOMIC_RELAXED, __HIP_MEMORY_SCOPE_AGENT);
        union { unsigned short u; __bf16 bf; } hh, hl;
        unsigned lo32 = (unsigned)pk, hi32 = (unsigned)(pk >> 32);
        hh.u = (unsigned short)(lo32 & 0xFFFF); hl.u = (unsigned short)(lo32 >> 16);
        float x0 = (float)hh.bf + (float)hl.bf;
        hh.u = (unsigned short)(hi32 & 0xFFFF); hl.u = (unsigned short)(hi32 >> 16);
        float x1 = (float)hh.bf + (float)hl.bf;
        acc += x0 * wt[(2 * k2) * O_ + o] + x1 * wt[(2 * k2 + 1) * O_ + o];
    }
    out[b * O_ + o] = acc + bfc[o];
}

// ---------------------------------------------------------------- launch

extern "C" void kernel_launch(void* const* d_in, const int* in_sizes, int n_in,
                              void* d_out, int out_size, void* d_ws, size_t ws_size,
                              hipStream_t stream) {
    const float* X     = (const float*)d_in[0];
    const float* Wih0  = (const float*)d_in[1];
    const float* Whh0  = (const float*)d_in[2];
    const float* bih0  = (const float*)d_in[3];
    const float* bhh0  = (const float*)d_in[4];
    const float* Wih1  = (const float*)d_in[5];
    const float* Whh1  = (const float*)d_in[6];
    const float* bih1  = (const float*)d_in[7];
    const float* bhh1  = (const float*)d_in[8];
    const float* Wfc   = (const float*)d_in[9];
    const float* bfc   = (const float*)d_in[10];
    float* out = (float*)d_out;

    char* p = (char*)d_ws;
    auto alloc = [&](size_t bytes) -> void* {
        void* r = (void*)p;
        p += (bytes + 255) & ~(size_t)255;
        return r;
    };
    const size_t nW0 = (size_t)H_ * I_;
    const size_t nW  = (size_t)H_ * H_;
    u64* xp      = (u64*)alloc((size_t)T_ * 16384 * 8);     // 33.5 MB
    __bf16* W0h  = (__bf16*)alloc(nW0 * 2);
    __bf16* W0l  = (__bf16*)alloc(nW0 * 2);
    __bf16* Wh0h = (__bf16*)alloc(nW * 2);
    __bf16* Wh0l = (__bf16*)alloc(nW * 2);
    __bf16* Wi1h = (__bf16*)alloc(nW * 2);
    __bf16* Wi1l = (__bf16*)alloc(nW * 2);
    __bf16* Wh1h = (__bf16*)alloc(nW * 2);
    __bf16* Wh1l = (__bf16*)alloc(nW * 2);
    u64* s0a  = (u64*)alloc(65536 * 8);
    u64* s0b  = (u64*)alloc(65536 * 8);
    u64* s1a  = (u64*)alloc(65536 * 8);
    u64* s1b  = (u64*)alloc(65536 * 8);
    float* wfct = (float*)alloc((size_t)H_ * O_ * 4);
    float* bs0  = (float*)alloc((size_t)H_ * 4);
    float* bs1  = (float*)alloc((size_t)H_ * 4);
    unsigned* bar = (unsigned*)alloc(4096);
    (void)ws_size; (void)n_in; (void)in_sizes; (void)out_size;

    pack_x<<<16384, 256, 0, stream>>>(X, xp);
    split_kernel<<<512, 256, 0, stream>>>(Wih0, W0h, W0l, (int)nW0);
    split_kernel<<<1024, 256, 0, stream>>>(Whh0, Wh0h, Wh0l, (int)nW);
    split_kernel<<<1024, 256, 0, stream>>>(Wih1, Wi1h, Wi1l, (int)nW);
    split_kernel<<<1024, 256, 0, stream>>>(Whh1, Wh1h, Wh1l, (int)nW);
    bias_sum_kernel<<<4, 256, 0, stream>>>(bih0, bhh0, bs0, H_);
    bias_sum_kernel<<<4, 256, 0, stream>>>(bih1, bhh1, bs1, H_);
    transpose_fc<<<(O_ * H_ + 255) / 256, 256, 0, stream>>>(Wfc, wfct);

    hipMemsetAsync(s0a, 0, 65536 * 8, stream);
    hipMemsetAsync(s1a, 0, 65536 * 8, stream);
    hipMemsetAsync(bar, 0, 4096, stream);

    PArgs args;
    args.xp = xp;
    args.Wi0h = W0h; args.Wi0l = W0l; args.Wr0h = Wh0h; args.Wr0l = Wh0l;
    args.Wi1h = Wi1h; args.Wi1l = Wi1l; args.Wr1h = Wh1h; args.Wr1l = Wh1l;
    args.bs0 = bs0; args.bs1 = bs1;
    args.s0a = s0a; args.s0b = s0b; args.s1a = s1a; args.s1b = s1b;
    args.bar = bar;
    void* kp[] = { &args };
    hipLaunchCooperativeKernel((void*)persistent_rnn, dim3(256), dim3(512), kp, 0, stream);

    // final layer1 state: last t1=255 (odd) wrote s1a
    fc_kernel<<<B_, O_, 0, stream>>>(s1a, wfct, bfc, out);
}